// Round 3
// baseline (115.177 us; speedup 1.0000x reference)
//
#include <hip/hip_runtime.h>
#include <math.h>

#define NBLOCKS 2048
#define NTHREADS 256

__device__ __forceinline__ float paired_iou(float4 pa, float4 pb)
{
    // xywh -> xyxy (match reference float32 rounding: x2 = x + w)
    float ax2 = pa.x + pa.z;
    float ay2 = pa.y + pa.w;
    float bx2 = pb.x + pb.z;
    float by2 = pb.y + pb.w;

    float ltx = fmaxf(pa.x, pb.x);
    float lty = fmaxf(pa.y, pb.y);
    float rbx = fminf(ax2, bx2);
    float rby = fminf(ay2, by2);

    float wx = fmaxf(rbx - ltx, 0.0f);
    float wy = fmaxf(rby - lty, 0.0f);
    float inter = wx * wy;

    float areaA = (ax2 - pa.x) * (ay2 - pa.y);
    float areaB = (bx2 - pb.x) * (by2 - pb.y);

    return inter / (areaA + areaB - inter);
}

// Single fused kernel: grid-stride streaming IoU sum (round-1 proven loop body,
// compiler-pipelined), per-block partial to d_ws, last-done block reduces the
// partials and writes -log(mean). Saves the second kernel launch.
__global__ __launch_bounds__(NTHREADS) void iou_fused_kernel(
    const float4* __restrict__ a,   // boxes_pred, xywh
    const float4* __restrict__ b,   // boxes, xywh
    float* __restrict__ partials,   // d_ws[0..NBLOCKS)
    unsigned int* __restrict__ counter, // d_ws + NBLOCKS (memset to 0 each call)
    float* __restrict__ out,
    int n)
{
    int tid = blockIdx.x * blockDim.x + threadIdx.x;
    int stride = gridDim.x * blockDim.x;

    float sum = 0.0f;
    for (int i = tid; i < n; i += stride) {
        float4 pa = a[i];
        float4 pb = b[i];
        sum += paired_iou(pa, pb);
    }

    // wave-64 shuffle reduction
    #pragma unroll
    for (int off = 32; off > 0; off >>= 1)
        sum += __shfl_down(sum, off, 64);

    __shared__ float smem[NTHREADS / 64];
    __shared__ bool isLast;
    int lane = threadIdx.x & 63;
    int wid  = threadIdx.x >> 6;
    if (lane == 0) smem[wid] = sum;
    __syncthreads();

    if (threadIdx.x == 0) {
        float t = 0.0f;
        #pragma unroll
        for (int w = 0; w < NTHREADS / 64; ++w) t += smem[w];
        partials[blockIdx.x] = t;         // deterministic per-block value
        __threadfence();                  // make partial visible device-wide
        unsigned int c = atomicAdd(counter, 1u);
        isLast = (c == gridDim.x - 1);
    }
    __syncthreads();

    if (isLast) {
        __threadfence();                  // acquire all partials
        double s = 0.0;
        for (int i = threadIdx.x; i < (int)gridDim.x; i += blockDim.x)
            s += (double)partials[i];

        #pragma unroll
        for (int off = 32; off > 0; off >>= 1)
            s += __shfl_down(s, off, 64);

        __shared__ double dsm[NTHREADS / 64];
        if (lane == 0) dsm[wid] = s;
        __syncthreads();

        if (threadIdx.x == 0) {
            double t = 0.0;
            #pragma unroll
            for (int w = 0; w < NTHREADS / 64; ++w) t += dsm[w];
            double mean = t / (double)n;
            out[0] = (float)(-log(mean));
        }
    }
}

extern "C" void kernel_launch(void* const* d_in, const int* in_sizes, int n_in,
                              void* d_out, int out_size, void* d_ws, size_t ws_size,
                              hipStream_t stream)
{
    const float4* boxes_pred = (const float4*)d_in[0];
    const float4* boxes      = (const float4*)d_in[1];
    float* out = (float*)d_out;
    float* partials = (float*)d_ws;                       // NBLOCKS floats
    unsigned int* counter = (unsigned int*)((float*)d_ws + NBLOCKS);

    int n = in_sizes[0] / 4;          // number of boxes

    // zero the arrival counter every call (graph-capturable, deterministic)
    hipMemsetAsync(counter, 0, sizeof(unsigned int), stream);

    iou_fused_kernel<<<NBLOCKS, NTHREADS, 0, stream>>>(
        boxes_pred, boxes, partials, counter, out, n);
}

// Round 4
// 50.896 us; speedup vs baseline: 2.2630x; 2.2630x over previous
//
#include <hip/hip_runtime.h>
#include <math.h>

#define NBLOCKS 2048
#define NTHREADS 256

typedef float f4 __attribute__((ext_vector_type(4)));

__device__ __forceinline__ float paired_iou(f4 pa, f4 pb)
{
    // xywh -> xyxy (match reference float32 rounding: x2 = x + w)
    float ax2 = pa.x + pa.z;
    float ay2 = pa.y + pa.w;
    float bx2 = pb.x + pb.z;
    float by2 = pb.y + pb.w;

    float ltx = fmaxf(pa.x, pb.x);
    float lty = fmaxf(pa.y, pb.y);
    float rbx = fminf(ax2, bx2);
    float rby = fminf(ay2, by2);

    float wx = fmaxf(rbx - ltx, 0.0f);
    float wy = fmaxf(rby - lty, 0.0f);
    float inter = wx * wy;

    float areaA = (ax2 - pa.x) * (ay2 - pa.y);
    float areaB = (bx2 - pb.x) * (by2 - pb.y);

    return inter / (areaA + areaB - inter);
}

__global__ __launch_bounds__(NTHREADS) void iou_partial_kernel(
    const f4* __restrict__ a,   // boxes_pred, xywh  (non-temporal: don't cache)
    const f4* __restrict__ b,   // boxes, xywh       (normal: let it own the L3)
    float* __restrict__ partials,
    int n)
{
    int tid = blockIdx.x * blockDim.x + threadIdx.x;
    int stride = gridDim.x * blockDim.x;

    float sum = 0.0f;
    for (int i = tid; i < n; i += stride) {
        f4 pa = __builtin_nontemporal_load(a + i);  // nt: stream from HBM
        f4 pb = b[i];                               // normal: L3-resident
        sum += paired_iou(pa, pb);
    }

    // wave-64 shuffle reduction
    #pragma unroll
    for (int off = 32; off > 0; off >>= 1)
        sum += __shfl_down(sum, off, 64);

    __shared__ float smem[NTHREADS / 64];
    int lane = threadIdx.x & 63;
    int wid  = threadIdx.x >> 6;
    if (lane == 0) smem[wid] = sum;
    __syncthreads();

    if (threadIdx.x == 0) {
        float t = 0.0f;
        #pragma unroll
        for (int w = 0; w < NTHREADS / 64; ++w) t += smem[w];
        partials[blockIdx.x] = t;   // written every call: deterministic
    }
}

__global__ __launch_bounds__(NTHREADS) void iou_final_kernel(
    const float* __restrict__ partials,
    float* __restrict__ out,
    int nblocks,
    int n)
{
    double sum = 0.0;
    for (int i = threadIdx.x; i < nblocks; i += blockDim.x)
        sum += (double)partials[i];

    #pragma unroll
    for (int off = 32; off > 0; off >>= 1)
        sum += __shfl_down(sum, off, 64);

    __shared__ double smem[NTHREADS / 64];
    int lane = threadIdx.x & 63;
    int wid  = threadIdx.x >> 6;
    if (lane == 0) smem[wid] = sum;
    __syncthreads();

    if (threadIdx.x == 0) {
        double t = 0.0;
        #pragma unroll
        for (int w = 0; w < NTHREADS / 64; ++w) t += smem[w];
        double mean = t / (double)n;
        out[0] = (float)(-log(mean));
    }
}

extern "C" void kernel_launch(void* const* d_in, const int* in_sizes, int n_in,
                              void* d_out, int out_size, void* d_ws, size_t ws_size,
                              hipStream_t stream)
{
    const f4* boxes_pred = (const f4*)d_in[0];
    const f4* boxes      = (const f4*)d_in[1];
    float* out = (float*)d_out;
    float* partials = (float*)d_ws;   // NBLOCKS floats = 8 KiB

    int n = in_sizes[0] / 4;          // number of boxes

    iou_partial_kernel<<<NBLOCKS, NTHREADS, 0, stream>>>(boxes_pred, boxes, partials, n);
    iou_final_kernel<<<1, NTHREADS, 0, stream>>>(partials, out, NBLOCKS, n);
}

// Round 5
// 48.813 us; speedup vs baseline: 2.3596x; 1.0427x over previous
//
#include <hip/hip_runtime.h>
#include <math.h>

#define NBLOCKS 2048
#define NTHREADS 256

typedef float f4 __attribute__((ext_vector_type(4)));

__device__ __forceinline__ float paired_iou(f4 pa, f4 pb)
{
    // xywh -> xyxy (match reference float32 rounding: x2 = x + w)
    float ax2 = pa.x + pa.z;
    float ay2 = pa.y + pa.w;
    float bx2 = pb.x + pb.z;
    float by2 = pb.y + pb.w;

    float ltx = fmaxf(pa.x, pb.x);
    float lty = fmaxf(pa.y, pb.y);
    float rbx = fminf(ax2, bx2);
    float rby = fminf(ay2, by2);

    float wx = fmaxf(rbx - ltx, 0.0f);
    float wy = fmaxf(rby - lty, 0.0f);
    float inter = wx * wy;

    float areaA = (ax2 - pa.x) * (ay2 - pa.y);
    float areaB = (bx2 - pb.x) * (by2 - pb.y);

    return inter / (areaA + areaB - inter);
}

__global__ __launch_bounds__(NTHREADS) void iou_partial_kernel(
    const f4* __restrict__ a,   // boxes_pred, xywh (non-temporal stream)
    const f4* __restrict__ b,   // boxes, xywh      (non-temporal stream)
    float* __restrict__ partials,
    int n)
{
    int tid = blockIdx.x * blockDim.x + threadIdx.x;
    int stride = gridDim.x * blockDim.x;

    float sum = 0.0f;
    for (int i = tid; i < n; i += stride) {
        f4 pa = __builtin_nontemporal_load(a + i);  // no cache allocation
        f4 pb = __builtin_nontemporal_load(b + i);  // no cache allocation
        sum += paired_iou(pa, pb);
    }

    // wave-64 shuffle reduction
    #pragma unroll
    for (int off = 32; off > 0; off >>= 1)
        sum += __shfl_down(sum, off, 64);

    __shared__ float smem[NTHREADS / 64];
    int lane = threadIdx.x & 63;
    int wid  = threadIdx.x >> 6;
    if (lane == 0) smem[wid] = sum;
    __syncthreads();

    if (threadIdx.x == 0) {
        float t = 0.0f;
        #pragma unroll
        for (int w = 0; w < NTHREADS / 64; ++w) t += smem[w];
        partials[blockIdx.x] = t;   // written every call: deterministic
    }
}

__global__ __launch_bounds__(NTHREADS) void iou_final_kernel(
    const float* __restrict__ partials,
    float* __restrict__ out,
    int nblocks,
    int n)
{
    double sum = 0.0;
    for (int i = threadIdx.x; i < nblocks; i += blockDim.x)
        sum += (double)partials[i];

    #pragma unroll
    for (int off = 32; off > 0; off >>= 1)
        sum += __shfl_down(sum, off, 64);

    __shared__ double smem[NTHREADS / 64];
    int lane = threadIdx.x & 63;
    int wid  = threadIdx.x >> 6;
    if (lane == 0) smem[wid] = sum;
    __syncthreads();

    if (threadIdx.x == 0) {
        double t = 0.0;
        #pragma unroll
        for (int w = 0; w < NTHREADS / 64; ++w) t += smem[w];
        double mean = t / (double)n;
        out[0] = (float)(-log(mean));
    }
}

extern "C" void kernel_launch(void* const* d_in, const int* in_sizes, int n_in,
                              void* d_out, int out_size, void* d_ws, size_t ws_size,
                              hipStream_t stream)
{
    const f4* boxes_pred = (const f4*)d_in[0];
    const f4* boxes      = (const f4*)d_in[1];
    float* out = (float*)d_out;
    float* partials = (float*)d_ws;   // NBLOCKS floats = 8 KiB

    int n = in_sizes[0] / 4;          // number of boxes

    iou_partial_kernel<<<NBLOCKS, NTHREADS, 0, stream>>>(boxes_pred, boxes, partials, n);
    iou_final_kernel<<<1, NTHREADS, 0, stream>>>(partials, out, NBLOCKS, n);
}